// Round 1
// baseline (699.820 us; speedup 1.0000x reference)
//
#include <hip/hip_runtime.h>
#include <cstddef>
#include <cstdint>

#define VOC 23
#define SEQ 256
#define NB  512
#define HID 4096
#define NCOL 11776    // SEQ*2*VOC
#define NPK 5888      // packed even-position cols: 128 * 46
#define KP  12288     // 3 * HID (split-bf16 triplets along K)
#define EPS_TIE 4e-5f // fp32-path net error tail <1e-5 -> 4x margin

__constant__ int INV23[VOC] = {0,1,12,8,6,14,4,10,3,18,7,21,2,16,5,20,13,19,9,17,15,11,22};

typedef __attribute__((ext_vector_type(8))) short short8;
typedef __attribute__((ext_vector_type(4))) float f32x4;

static __device__ __forceinline__ unsigned int f2bf(float f) {
  unsigned int x = __float_as_uint(f);
  return (x + 0x7fffu + ((x >> 16) & 1u)) >> 16;   // RNE, finite inputs
}
static __device__ __forceinline__ float bf2f(unsigned int u) {
  return __uint_as_float(u << 16);
}

#define GL2LDS(g, l) __builtin_amdgcn_global_load_lds(                      \
    (const __attribute__((address_space(1))) unsigned int*)(g),             \
    (__attribute__((address_space(3))) unsigned int*)(l), 16, 0, 0)

// K1: token extraction + odd-row copy
__global__ __launch_bounds__(256) void k_tok_copy(const float* __restrict__ in,
                                                  float* __restrict__ out,
                                                  int* __restrict__ tok) {
  const int b = blockIdx.x;
  const int l = threadIdx.x;
  const float* row = in + ((size_t)b * SEQ + l) * VOC;
  int t = 0; float best = -1.0f;
#pragma unroll
  for (int v = 0; v < VOC; ++v) { float x = row[v]; if (x > best) { best = x; t = v; } }
  tok[b * SEQ + l] = t;
  if (l & 1) {
    float* o = out + ((size_t)b * SEQ + l) * VOC;
#pragma unroll
    for (int v = 0; v < VOC; ++v) o[v] = row[v];
  }
}

// Repack W2 -> Bp bf16 B^T [NPK rows][KP cols], triplets per k: [hi, lo, hi].
// 64x64 (k x j) tile, transpose through LDS.
__global__ __launch_bounds__(256) void k_pack_w2(const float* __restrict__ W2,
                                                 unsigned short* __restrict__ Bp) {
  const int k0 = blockIdx.x * 64;   // 64 k-tiles
  const int j0 = blockIdx.y * 64;   // 92 j-tiles
  const int tid = threadIdx.x;
  __shared__ float T[64 * 65];
#pragma unroll
  for (int it = 0; it < 16; ++it) {
    int idx = it * 256 + tid;
    int k_l = idx >> 6, j_l = idx & 63;
    int j = j0 + j_l;
    int ee = j / 46, cc = j - ee * 46;          // packed j -> W2 col 92e+c
    T[j_l * 65 + k_l] = W2[(size_t)(k0 + k_l) * NCOL + 92 * ee + cc];
  }
  __syncthreads();
  const int j_l = tid >> 2, qt = tid & 3;       // 4 threads per output row
  unsigned int d[24];
#pragma unroll
  for (int pr = 0; pr < 8; ++pr) {              // 8 pairs of k = 16 k-units
    int k_l = qt * 16 + pr * 2;
    float va = T[j_l * 65 + k_l], vb = T[j_l * 65 + k_l + 1];
    unsigned int ha = f2bf(va), la = f2bf(va - bf2f(ha));
    unsigned int hb = f2bf(vb), lb = f2bf(vb - bf2f(hb));
    // elems: ha, la, ha | hb, lb, hb  (B triplet = [Bh, Bl, Bh])
    d[pr * 3 + 0] = ha | (la << 16);
    d[pr * 3 + 1] = ha | (hb << 16);
    d[pr * 3 + 2] = lb | (hb << 16);
  }
  char* dst = ((char*)Bp) + (size_t)(j0 + j_l) * (KP * 2) + 6 * k0 + 96 * qt;
#pragma unroll
  for (int u = 0; u < 6; ++u) {
    uint4 w = make_uint4(d[4 * u], d[4 * u + 1], d[4 * u + 2], d[4 * u + 3]);
    ((uint4*)dst)[u] = w;
  }
}

// K2: h = relu(b1 + sum of 128 gathered W1 rows); also emit Ap bf16 triplets [hi,hi,lo]
__global__ __launch_bounds__(256) void k_hidden(const float* __restrict__ W1,
                                                const float* __restrict__ b1,
                                                const int* __restrict__ tok,
                                                float* __restrict__ h,
                                                unsigned short* __restrict__ Ap) {
  const int b = blockIdx.x;
  const int tid = threadIdx.x;
  __shared__ int rowS[128];
  if (tid < 128) {
    const int l = 2 * tid + 1;
    rowS[tid] = l * VOC + tok[b * SEQ + l];
  }
  __syncthreads();
  float4 acc[4];
#pragma unroll
  for (int j = 0; j < 4; ++j) acc[j] = make_float4(0.f, 0.f, 0.f, 0.f);
  for (int i = 0; i < 128; i += 2) {
    const float4* wr0 = (const float4*)(W1 + (size_t)rowS[i] * HID);
    const float4* wr1 = (const float4*)(W1 + (size_t)rowS[i + 1] * HID);
    float4 w0[4], w1[4];
#pragma unroll
    for (int j = 0; j < 4; ++j) w0[j] = wr0[tid + 256 * j];
#pragma unroll
    for (int j = 0; j < 4; ++j) w1[j] = wr1[tid + 256 * j];
#pragma unroll
    for (int j = 0; j < 4; ++j) {
      acc[j].x += w0[j].x; acc[j].y += w0[j].y; acc[j].z += w0[j].z; acc[j].w += w0[j].w;
      acc[j].x += w1[j].x; acc[j].y += w1[j].y; acc[j].z += w1[j].z; acc[j].w += w1[j].w;
    }
  }
  float4* hb = (float4*)(h + (size_t)b * HID);
  const float4* bv = (const float4*)b1;
#pragma unroll
  for (int j = 0; j < 4; ++j) {
    float4 bb = bv[tid + 256 * j];
    float4 r;
    r.x = fmaxf(acc[j].x + bb.x, 0.f);
    r.y = fmaxf(acc[j].y + bb.y, 0.f);
    r.z = fmaxf(acc[j].z + bb.z, 0.f);
    r.w = fmaxf(acc[j].w + bb.w, 0.f);
    hb[tid + 256 * j] = r;
    // split-bf16 A triplets: per elem [hi, hi, lo]
    unsigned int h0 = f2bf(r.x), L0 = f2bf(r.x - bf2f(h0));
    unsigned int h1 = f2bf(r.y), L1 = f2bf(r.y - bf2f(h1));
    unsigned int h2 = f2bf(r.z), L2 = f2bf(r.z - bf2f(h2));
    unsigned int h3 = f2bf(r.w), L3 = f2bf(r.w - bf2f(h3));
    uint2* ap = (uint2*)(((char*)Ap) + (size_t)b * (KP * 2) + 24 * (tid + 256 * j));
    ap[0] = make_uint2(h0 | (h0 << 16), L0 | (h1 << 16));
    ap[1] = make_uint2(h1 | (L1 << 16), h2 | (h2 << 16));
    ap[2] = make_uint2(L2 | (h3 << 16), h3 | (L3 << 16));
  }
}

// K3 v2: bf16 MFMA GEMM. 128x128 tile, BK=32 double-buffered (2-phase),
// XOR-swizzled LDS (pre-swizzled global source, linear global_load_lds dest),
// bijective XCD-chunked block swizzle (736 = 8*92).
// LDS layout per 8KB buffer: 64 lines x 128B; line holds M-rows {2L,2L+1};
// physical granule gph = ((row&1)*4 + q) ^ (line&7)  -> 2-way (free) on ds_read_b128.
// MFMA accumulation order is bit-identical to v1 (same chunk/kk/k order).
#define STAGE(bufA, bufB, kbv) do {                                               \
    _Pragma("unroll")                                                             \
    for (int c_ = 0; c_ < 2; ++c_) {                                              \
      GL2LDS(((const char*)Ap) + aG[c_] + (kbv), ((char*)(bufA)) + ldsOff[c_]);   \
      GL2LDS(((const char*)Bp) + bG[c_] + (kbv), ((char*)(bufB)) + ldsOff[c_]);   \
    }                                                                             \
  } while (0)

#define COMPUTE(bufA, bufB) do {                                                  \
    short8 a_[4], b_[4];                                                          \
    _Pragma("unroll")                                                             \
    for (int i_ = 0; i_ < 4; ++i_)                                                \
      a_[i_] = *(const short8*)((const char*)(bufA) + aoff + 1024 * i_);          \
    _Pragma("unroll")                                                             \
    for (int j_ = 0; j_ < 4; ++j_)                                                \
      b_[j_] = *(const short8*)((const char*)(bufB) + boff + 1024 * j_);          \
    _Pragma("unroll")                                                             \
    for (int i_ = 0; i_ < 4; ++i_)                                                \
      _Pragma("unroll")                                                           \
      for (int j_ = 0; j_ < 4; ++j_)                                              \
        acc[i_][j_] = __builtin_amdgcn_mfma_f32_16x16x32_bf16(a_[i_], b_[j_],     \
                                                              acc[i_][j_], 0, 0, 0); \
  } while (0)

__global__ __launch_bounds__(256) void k3_mfma(const unsigned short* __restrict__ Ap,
                                               const unsigned short* __restrict__ Bp,
                                               float* __restrict__ partial) {
  __shared__ unsigned short AsmD[2][128 * 32];
  __shared__ unsigned short BsmD[2][128 * 32];
  const int tid = threadIdx.x;

  // XCD-chunked bijective swizzle: f -> nf so each XCD's contiguous run covers
  // whole (n-tile x 16-block) groups -> the 4m x 4s blocks sharing a B panel
  // land on one XCD's L2.
  const int f = blockIdx.x;
  const int nf = (f & 7) * 92 + (f >> 3);         // 736 = 8*92, bijective
  const int bn0 = (nf >> 4) * 128;                // n-tile 0..45
  const int inner = nf & 15;
  const int bm0 = (inner & 3) * 128;              // m-tile 0..3
  const int s = inner >> 2;                       // split 0..3

  const int lane = tid & 63, wave = tid >> 6;
  const int wm = wave & 1, wn = wave >> 1;
  const int r = lane & 15, q = lane >> 4;

  // Staging: LDS dest is linear granule G = c*256+tid (HW: uniform base + lane*16);
  // global source pre-swizzled: invert gph -> logical (row, ku-block).
  size_t aG[2], bG[2]; int ldsOff[2];
#pragma unroll
  for (int c = 0; c < 2; ++c) {
    const int G = c * 256 + tid;
    const int line = G >> 3, gph = G & 7;
    const int gin = gph ^ (line & 7);
    const int grow = 2 * line + (gin >> 2);
    const int gcol = (gin & 3) << 4;
    aG[c] = (size_t)(bm0 + grow) * (KP * 2) + gcol;
    bG[c] = (size_t)(bn0 + grow) * (KP * 2) + gcol;
    ldsOff[c] = G * 16;
  }

  // Swizzled fragment-read offsets: row = 64w + 16i + r -> line = 32w + 8i + (r>>1),
  // line&7 == (r>>1)&7, so gph is a per-lane constant; frag i advances by 1024B.
  const int gphR = (((((r & 1) << 2) | q) ^ ((r >> 1) & 7)) << 4);
  const int aoff = (32 * wm + (r >> 1)) * 128 + gphR;
  const int boff = (32 * wn + (r >> 1)) * 128 + gphR;

  f32x4 acc[4][4];
#pragma unroll
  for (int i = 0; i < 4; ++i)
#pragma unroll
    for (int j = 0; j < 4; ++j) acc[i][j] = (f32x4){0.f, 0.f, 0.f, 0.f};

  const int kb0 = s * 6144;    // byte offset of this split's K range (per row)
  STAGE(AsmD[0], BsmD[0], kb0);
  __syncthreads();             // compiler emits vmcnt(0) before barrier: buf0 ready
#pragma unroll 1
  for (int it = 0; it < 96; it += 2) {
    const int kb = kb0 + it * 64;
    STAGE(AsmD[1], BsmD[1], kb + 64);   // prefetch next chunk, overlaps compute
    COMPUTE(AsmD[0], BsmD[0]);
    __syncthreads();                    // drains vmcnt after a full compute phase
    if (it < 94) STAGE(AsmD[0], BsmD[0], kb + 128);
    COMPUTE(AsmD[1], BsmD[1]);
    __syncthreads();
  }

  float* pbase = partial + (size_t)s * NB * NPK;
#pragma unroll
  for (int i = 0; i < 4; ++i) {
    const int m = bm0 + 64 * wm + 16 * i + 4 * q;   // C row = quad*4+reg
#pragma unroll
    for (int j = 0; j < 4; ++j) {
      const int n = bn0 + 64 * wn + 16 * j + r;     // C col = lane&15
      float* pp = pbase + (size_t)m * NPK + n;
#pragma unroll
      for (int reg = 0; reg < 4; ++reg)
        pp[(size_t)reg * NPK] = acc[i][j][reg];
    }
  }
}

// Epilogue: sum 4 partials + b2, argmax both groups, flag ties, write one-hot rows.
__global__ __launch_bounds__(256) void k_epilogue(const float* __restrict__ partial,
                                                  const float* __restrict__ b2,
                                                  const int* __restrict__ tok,
                                                  int* __restrict__ win,
                                                  int* __restrict__ gcnt,
                                                  int* __restrict__ glist,
                                                  float* __restrict__ out) {
  const int b = blockIdx.x, tid = threadIdx.x;
  const int e = tid >> 1, grp = tid & 1;
  __shared__ int winS[256];
  __shared__ int flagS[256];
  float x[VOC];
  const size_t base = (size_t)b * NPK + 46 * e + 23 * grp;
#pragma unroll
  for (int c = 0; c < VOC; ++c) x[c] = b2[92 * e + 23 * grp + c];
#pragma unroll
  for (int s2 = 0; s2 < 4; ++s2) {
    const float* pp = partial + (size_t)s2 * NB * NPK + base;
#pragma unroll
    for (int c = 0; c < VOC; ++c) x[c] += pp[c];
  }
  float b0 = -1e30f, b1v = -1e30f; int bi = 0;
#pragma unroll
  for (int c = 0; c < VOC; ++c) {
    if (x[c] > b0) { b1v = b0; b0 = x[c]; bi = c; }
    else if (x[c] > b1v) b1v = x[c];
  }
  winS[tid] = bi;
  flagS[tid] = (b0 - b1v < EPS_TIE) ? 1 : 0;
  __syncthreads();
  if (!grp) {
    const int loc = winS[tid], sc = winS[tid + 1];
    win[b * 256 + 2 * e] = loc;
    win[b * 256 + 2 * e + 1] = sc;
    const int f0 = flagS[tid], f1 = flagS[tid + 1];
    if (f0 | f1) {
      int idx = atomicAdd(gcnt, 1);
      glist[idx] = e | (b << 7) | (f0 << 16) | (f1 << 17);
    }
    const int l = 2 * e;
    float* o = out + ((size_t)b * SEQ + l) * VOC;
    if (sc == 0) {
      for (int v = 0; v < VOC; ++v) o[v] = 0.f;
    } else {
      const int t = tok[b * SEQ + l];
      int dd = t - loc; if (dd < 0) dd += VOC;
      const int u = (INV23[sc] * dd) % VOC;
      for (int v = 0; v < VOC; ++v) o[v] = (v == u) ? 1.f : 0.f;
    }
  }
}

// fp64 recheck of flagged near-ties, from original fp32 h and W2. Fixed grid.
__global__ __launch_bounds__(192) void k_recheck(const float* __restrict__ h,
                                                 const float* __restrict__ W2,
                                                 const float* __restrict__ b2,
                                                 const int* __restrict__ tok,
                                                 const int* __restrict__ win,
                                                 const int* __restrict__ gcnt,
                                                 const int* __restrict__ glist,
                                                 float* __restrict__ out) {
  const int tid = threadIdx.x;
  __shared__ double dpart[184];
  __shared__ double dlog[VOC];
  __shared__ int decS[2];
  const int n = gcnt[0];
  for (int ei = blockIdx.x; ei < n; ei += 128) {
    const int ent = glist[ei];
    const int e = ent & 127, b = (ent >> 7) & 511;
    const int l = 2 * e;
#pragma unroll
    for (int grp = 0; grp < 2; ++grp) {
      if (!(ent & (1 << (16 + grp)))) {
        if (tid == 0) decS[grp] = win[b * 256 + 2 * e + grp];
      } else {
        const int col0 = 92 * e + 23 * grp;
        if (tid < 184) {
          const int c = tid >> 3, part = tid & 7;
          const float* hb = h + (size_t)b * HID;
          const size_t colc = (size_t)(col0 + c);
          double sacc[8] = {0, 0, 0, 0, 0, 0, 0, 0};
          const int kbase = part * 512;
          for (int kk = 0; kk < 512; kk += 8) {
#pragma unroll
            for (int t2 = 0; t2 < 8; ++t2) {
              const int k = kbase + kk + t2;
              sacc[t2] += (double)hb[k] * (double)W2[(size_t)k * NCOL + colc];
            }
          }
          dpart[tid] = ((sacc[0] + sacc[1]) + (sacc[2] + sacc[3])) +
                       ((sacc[4] + sacc[5]) + (sacc[6] + sacc[7]));
        }
        __syncthreads();
        if (tid < VOC) {
          double sd = (double)b2[col0 + tid];
#pragma unroll
          for (int p2 = 0; p2 < 8; ++p2) sd += dpart[tid * 8 + p2];
          dlog[tid] = sd;
        }
        __syncthreads();
        if (tid == 0) {
          double best = -1e300; int bi2 = 0;
#pragma unroll
          for (int c = 0; c < VOC; ++c)
            if (dlog[c] > best) { best = dlog[c]; bi2 = c; }
          decS[grp] = bi2;
        }
      }
      __syncthreads();
    }
    if (tid < VOC) {
      const int loc = decS[0], sc = decS[1];
      float val = 0.f;
      if (sc != 0) {
        const int t = tok[b * SEQ + l];
        int dd = t - loc; if (dd < 0) dd += VOC;
        const int u = (INV23[sc] * dd) % VOC;
        val = (tid == u) ? 1.f : 0.f;
      }
      out[((size_t)b * SEQ + l) * VOC + tid] = val;
    }
    __syncthreads();
  }
}

extern "C" void kernel_launch(void* const* d_in, const int* in_sizes, int n_in,
                              void* d_out, int out_size, void* d_ws, size_t ws_size,
                              hipStream_t stream) {
  const float* in  = (const float*)d_in[0];
  const float* W1  = (const float*)d_in[2];
  const float* b1  = (const float*)d_in[3];
  const float* W2  = (const float*)d_in[4];
  const float* b2  = (const float*)d_in[5];
  float* out = (float*)d_out;

  char* w = (char*)d_ws;
  int* tok = (int*)w;                         w += (size_t)NB * SEQ * 4;          // 0.5 MB
  float* h = (float*)w;                       w += (size_t)NB * HID * 4;          // 8 MB
  unsigned short* Ap = (unsigned short*)w;    w += (size_t)NB * KP * 2;           // 12.6 MB
  unsigned short* Bp = (unsigned short*)w;    w += (size_t)NPK * KP * 2;          // 144.7 MB
  float* partial = (float*)w;                 w += (size_t)4 * NB * NPK * 4;      // 48.2 MB
  int* win = (int*)w;                         w += (size_t)NB * 256 * 4;          // 0.5 MB
  int* gcnt = (int*)w;                        w += 256;
  int* glist = (int*)w;                       w += (size_t)65536 * 4;             // 0.26 MB

  k_tok_copy<<<dim3(NB), dim3(256), 0, stream>>>(in, out, tok);
  k_pack_w2<<<dim3(64, 92), dim3(256), 0, stream>>>(W2, Bp);
  k_hidden<<<dim3(NB), dim3(256), 0, stream>>>(W1, b1, tok, h, Ap);
  hipMemsetAsync(gcnt, 0, 4, stream);
  k3_mfma<<<dim3(736), dim3(256), 0, stream>>>(Ap, Bp, partial);
  k_epilogue<<<dim3(NB), dim3(256), 0, stream>>>(partial, b2, tok, win, gcnt, glist, out);
  k_recheck<<<dim3(128), dim3(192), 0, stream>>>(h, W2, b2, tok, win, gcnt, glist, out);
}

// Round 2
// 621.896 us; speedup vs baseline: 1.1253x; 1.1253x over previous
//
#include <hip/hip_runtime.h>
#include <cstddef>
#include <cstdint>

#define VOC 23
#define SEQ 256
#define NB  512
#define HID 4096
#define NCOL 11776    // SEQ*2*VOC
#define NPK 5888      // packed even-position cols: 128 * 46
#define KP  12288     // 3 * HID (split-bf16 triplets along K)
#define EPS_TIE 4e-5f // fp32-path net error tail <1e-5 -> 4x margin

__constant__ int INV23[VOC] = {0,1,12,8,6,14,4,10,3,18,7,21,2,16,5,20,13,19,9,17,15,11,22};

typedef __attribute__((ext_vector_type(8))) short short8;
typedef __attribute__((ext_vector_type(4))) float f32x4;

static __device__ __forceinline__ unsigned int f2bf(float f) {
  unsigned int x = __float_as_uint(f);
  return (x + 0x7fffu + ((x >> 16) & 1u)) >> 16;   // RNE, finite inputs
}
static __device__ __forceinline__ float bf2f(unsigned int u) {
  return __uint_as_float(u << 16);
}

#define GL2LDS(g, l) __builtin_amdgcn_global_load_lds(                      \
    (const __attribute__((address_space(1))) unsigned int*)(g),             \
    (__attribute__((address_space(3))) unsigned int*)(l), 16, 0, 0)

// K1: token extraction + odd-row copy
__global__ __launch_bounds__(256) void k_tok_copy(const float* __restrict__ in,
                                                  float* __restrict__ out,
                                                  int* __restrict__ tok) {
  const int b = blockIdx.x;
  const int l = threadIdx.x;
  const float* row = in + ((size_t)b * SEQ + l) * VOC;
  int t = 0; float best = -1.0f;
#pragma unroll
  for (int v = 0; v < VOC; ++v) { float x = row[v]; if (x > best) { best = x; t = v; } }
  tok[b * SEQ + l] = t;
  if (l & 1) {
    float* o = out + ((size_t)b * SEQ + l) * VOC;
#pragma unroll
    for (int v = 0; v < VOC; ++v) o[v] = row[v];
  }
}

// Repack W2 -> Bp bf16 B^T [NPK rows][KP cols], triplets per k: [hi, lo, hi].
// 64x64 (k x j) tile, transpose through LDS.
__global__ __launch_bounds__(256) void k_pack_w2(const float* __restrict__ W2,
                                                 unsigned short* __restrict__ Bp) {
  const int k0 = blockIdx.x * 64;   // 64 k-tiles
  const int j0 = blockIdx.y * 64;   // 92 j-tiles
  const int tid = threadIdx.x;
  __shared__ float T[64 * 65];
#pragma unroll
  for (int it = 0; it < 16; ++it) {
    int idx = it * 256 + tid;
    int k_l = idx >> 6, j_l = idx & 63;
    int j = j0 + j_l;
    int ee = j / 46, cc = j - ee * 46;          // packed j -> W2 col 92e+c
    T[j_l * 65 + k_l] = W2[(size_t)(k0 + k_l) * NCOL + 92 * ee + cc];
  }
  __syncthreads();
  const int j_l = tid >> 2, qt = tid & 3;       // 4 threads per output row
  unsigned int d[24];
#pragma unroll
  for (int pr = 0; pr < 8; ++pr) {              // 8 pairs of k = 16 k-units
    int k_l = qt * 16 + pr * 2;
    float va = T[j_l * 65 + k_l], vb = T[j_l * 65 + k_l + 1];
    unsigned int ha = f2bf(va), la = f2bf(va - bf2f(ha));
    unsigned int hb = f2bf(vb), lb = f2bf(vb - bf2f(hb));
    // elems: ha, la, ha | hb, lb, hb  (B triplet = [Bh, Bl, Bh])
    d[pr * 3 + 0] = ha | (la << 16);
    d[pr * 3 + 1] = ha | (hb << 16);
    d[pr * 3 + 2] = lb | (hb << 16);
  }
  char* dst = ((char*)Bp) + (size_t)(j0 + j_l) * (KP * 2) + 6 * k0 + 96 * qt;
#pragma unroll
  for (int u = 0; u < 6; ++u) {
    uint4 w = make_uint4(d[4 * u], d[4 * u + 1], d[4 * u + 2], d[4 * u + 3]);
    ((uint4*)dst)[u] = w;
  }
}

// K2: h = relu(b1 + sum of 128 gathered W1 rows); also emit Ap bf16 triplets [hi,hi,lo]
__global__ __launch_bounds__(256) void k_hidden(const float* __restrict__ W1,
                                                const float* __restrict__ b1,
                                                const int* __restrict__ tok,
                                                float* __restrict__ h,
                                                unsigned short* __restrict__ Ap) {
  const int b = blockIdx.x;
  const int tid = threadIdx.x;
  __shared__ int rowS[128];
  if (tid < 128) {
    const int l = 2 * tid + 1;
    rowS[tid] = l * VOC + tok[b * SEQ + l];
  }
  __syncthreads();
  float4 acc[4];
#pragma unroll
  for (int j = 0; j < 4; ++j) acc[j] = make_float4(0.f, 0.f, 0.f, 0.f);
  for (int i = 0; i < 128; i += 2) {
    const float4* wr0 = (const float4*)(W1 + (size_t)rowS[i] * HID);
    const float4* wr1 = (const float4*)(W1 + (size_t)rowS[i + 1] * HID);
    float4 w0[4], w1[4];
#pragma unroll
    for (int j = 0; j < 4; ++j) w0[j] = wr0[tid + 256 * j];
#pragma unroll
    for (int j = 0; j < 4; ++j) w1[j] = wr1[tid + 256 * j];
#pragma unroll
    for (int j = 0; j < 4; ++j) {
      acc[j].x += w0[j].x; acc[j].y += w0[j].y; acc[j].z += w0[j].z; acc[j].w += w0[j].w;
      acc[j].x += w1[j].x; acc[j].y += w1[j].y; acc[j].z += w1[j].z; acc[j].w += w1[j].w;
    }
  }
  float4* hb = (float4*)(h + (size_t)b * HID);
  const float4* bv = (const float4*)b1;
#pragma unroll
  for (int j = 0; j < 4; ++j) {
    float4 bb = bv[tid + 256 * j];
    float4 r;
    r.x = fmaxf(acc[j].x + bb.x, 0.f);
    r.y = fmaxf(acc[j].y + bb.y, 0.f);
    r.z = fmaxf(acc[j].z + bb.z, 0.f);
    r.w = fmaxf(acc[j].w + bb.w, 0.f);
    hb[tid + 256 * j] = r;
    // split-bf16 A triplets: per elem [hi, hi, lo]
    unsigned int h0 = f2bf(r.x), L0 = f2bf(r.x - bf2f(h0));
    unsigned int h1 = f2bf(r.y), L1 = f2bf(r.y - bf2f(h1));
    unsigned int h2 = f2bf(r.z), L2 = f2bf(r.z - bf2f(h2));
    unsigned int h3 = f2bf(r.w), L3 = f2bf(r.w - bf2f(h3));
    uint2* ap = (uint2*)(((char*)Ap) + (size_t)b * (KP * 2) + 24 * (tid + 256 * j));
    ap[0] = make_uint2(h0 | (h0 << 16), L0 | (h1 << 16));
    ap[1] = make_uint2(h1 | (L1 << 16), h2 | (h2 << 16));
    ap[2] = make_uint2(L2 | (h3 << 16), h3 | (L3 << 16));
  }
}

// K3 v3: bf16 MFMA GEMM, T3+T4 deep pipeline.
// 256x256 tile, BK=32, 512 thr (8 waves, 2M x 4N; wave tile 128x64).
// Ring-4 LDS (4 slots x [A 16KB | B 16KB] = 128KB), ONE s_barrier per K-step,
// vmcnt NEVER drained in the loop (steady-state vmcnt(8): 2 stages of 4 loads fly).
// Ledger: prologue issues stages t=0,1,2. Loop t: vmcnt(8) certifies own loads of
// stage(t) retired (in-order retire), s_barrier globalizes; ds_read frags(t);
// issue stage(t+3) into slot (t+3)&3 -- its last readers (t-1) retired their
// ds_reads before barrier(t), so no second barrier needed. Tail peels 8->4->0.
// Swizzle (round-1-verified, 0 conflicts): 2 rows per 128B line,
// gph = ((row&1)*4+q) ^ (line&7); stage source pre-swizzled, LDS dest linear.
// K accumulation order = 96 ascending K=32 slices, bit-identical to v1/v2.
__global__ __launch_bounds__(512, 2) void k3_mfma(const unsigned short* __restrict__ Ap,
                                                  const unsigned short* __restrict__ Bp,
                                                  float* __restrict__ partial) {
  __shared__ char lds3[4 * 32768];   // 4 slots: [A 16KB][B 16KB]
  const int tid = threadIdx.x;

  // 184 = 8 XCD * 23: bijective chunking; consecutive d on one XCD pair the two
  // m-tiles of each (n,s) B-panel (L2 dedup) and share ~1 s-region's A slabs.
  const int f = blockIdx.x;
  const int d = (f & 7) * 23 + (f >> 3);
  const int g = d >> 1, mi = d & 1;
  const int s = g / 23, n = g - s * 23;
  const int bm0 = mi * 256;
  const int bn0 = n * 256;
  const int kb0 = s * 6144;          // byte offset of this split's K range per row

  const int lane = tid & 63, wave = tid >> 6;
  const int wm = wave & 1, wn = wave >> 1;     // 2M x 4N wave grid
  const int r = lane & 15, q = lane >> 4;

  // Stage addressing: linear LDS granule G (uniform base + lane*16), global
  // source pre-swizzled (invert gph).  c<2: A granules, c>=2: B granules.
  size_t gsrc[4]; int gdst[4];
#pragma unroll
  for (int c = 0; c < 4; ++c) {
    const int G = (c & 1) * 512 + tid;          // 0..1023
    const int line = G >> 3, gph = G & 7;
    const int gin = gph ^ (line & 7);
    const int grow = 2 * line + (gin >> 2);     // tile row 0..255
    const int gcol = (gin & 3) << 4;            // 0/16/32/48 within 64B K-slice
    const int row0 = (c < 2 ? bm0 : bn0) + grow;
    gsrc[c] = (size_t)row0 * (KP * 2) + gcol;
    gdst[c] = G * 16;
  }

#define STAGE3(slot, kbv) do {                                                    \
    char* ldsb_ = lds3 + ((slot) << 15);                                          \
    GL2LDS(((const char*)Ap) + gsrc[0] + (kbv), ldsb_ + gdst[0]);                 \
    GL2LDS(((const char*)Ap) + gsrc[1] + (kbv), ldsb_ + gdst[1]);                 \
    GL2LDS(((const char*)Bp) + gsrc[2] + (kbv), ldsb_ + 16384 + gdst[2]);         \
    GL2LDS(((const char*)Bp) + gsrc[3] + (kbv), ldsb_ + 16384 + gdst[3]);         \
  } while (0)

  // Fragment read offsets (swizzled): row = base + 16u + r -> line&7 = (r>>1)&7
  // (per-lane constant), granule-in-row = q.
  const int gphR = (((((r & 1) << 2) | q) ^ ((r >> 1) & 7)) << 4);
  const int aoff = (wm * 64 + (r >> 1)) * 128 + gphR;   // + i*1024, i=0..7
  const int boff = (wn * 32 + (r >> 1)) * 128 + gphR;   // + j*1024, j=0..3

  f32x4 acc[8][4];
#pragma unroll
  for (int i = 0; i < 8; ++i)
#pragma unroll
    for (int j = 0; j < 4; ++j) acc[i][j] = (f32x4){0.f, 0.f, 0.f, 0.f};

#define COMPUTE3(slot) do {                                                       \
    const char* sb_ = lds3 + ((slot) << 15);                                      \
    short8 a_[8], b_[4];                                                          \
    _Pragma("unroll")                                                             \
    for (int i_ = 0; i_ < 8; ++i_)                                                \
      a_[i_] = *(const short8*)(sb_ + aoff + i_ * 1024);                          \
    _Pragma("unroll")                                                             \
    for (int j_ = 0; j_ < 4; ++j_)                                                \
      b_[j_] = *(const short8*)(sb_ + 16384 + boff + j_ * 1024);                  \
    __builtin_amdgcn_s_setprio(1);                                                \
    _Pragma("unroll")                                                             \
    for (int i_ = 0; i_ < 8; ++i_)                                                \
      _Pragma("unroll")                                                           \
      for (int j_ = 0; j_ < 4; ++j_)                                              \
        acc[i_][j_] = __builtin_amdgcn_mfma_f32_16x16x32_bf16(a_[i_], b_[j_],     \
                                                              acc[i_][j_], 0, 0, 0); \
    __builtin_amdgcn_s_setprio(0);                                                \
  } while (0)

  // Prologue: 3 stages in flight (12 loads).
  STAGE3(0, kb0);
  STAGE3(1, kb0 + 64);
  STAGE3(2, kb0 + 128);

#pragma unroll 1
  for (int t = 0; t < 93; ++t) {               // NT=96, last staged here: t=92 -> 95
    asm volatile("s_waitcnt vmcnt(8)" ::: "memory");
    __builtin_amdgcn_s_barrier();
    __builtin_amdgcn_sched_barrier(0);
    const int slot = t & 3;
    {
      const char* sb_ = lds3 + (slot << 15);
      short8 a_[8], b_[4];
#pragma unroll
      for (int i_ = 0; i_ < 8; ++i_)
        a_[i_] = *(const short8*)(sb_ + aoff + i_ * 1024);
#pragma unroll
      for (int j_ = 0; j_ < 4; ++j_)
        b_[j_] = *(const short8*)(sb_ + 16384 + boff + j_ * 1024);
      STAGE3((t + 3) & 3, kb0 + (t + 3) * 64); // hazard-free: readers of (t-1) done
      __builtin_amdgcn_s_setprio(1);
#pragma unroll
      for (int i_ = 0; i_ < 8; ++i_)
#pragma unroll
        for (int j_ = 0; j_ < 4; ++j_)
          acc[i_][j_] = __builtin_amdgcn_mfma_f32_16x16x32_bf16(a_[i_], b_[j_],
                                                                acc[i_][j_], 0, 0, 0);
      __builtin_amdgcn_s_setprio(0);
    }
  }
  // Tail peel: t = 93, 94, 95 (no more stages; drain 8 -> 4 -> 0).
  asm volatile("s_waitcnt vmcnt(8)" ::: "memory");
  __builtin_amdgcn_s_barrier();
  __builtin_amdgcn_sched_barrier(0);
  COMPUTE3(93 & 3);
  asm volatile("s_waitcnt vmcnt(4)" ::: "memory");
  __builtin_amdgcn_s_barrier();
  __builtin_amdgcn_sched_barrier(0);
  COMPUTE3(94 & 3);
  asm volatile("s_waitcnt vmcnt(0)" ::: "memory");
  __builtin_amdgcn_s_barrier();
  __builtin_amdgcn_sched_barrier(0);
  COMPUTE3(95 & 3);

  float* pbase = partial + (size_t)s * NB * NPK;
#pragma unroll
  for (int i = 0; i < 8; ++i) {
    const int m = bm0 + wm * 128 + 16 * i + 4 * q;   // C row = quad*4+reg
#pragma unroll
    for (int j = 0; j < 4; ++j) {
      const int nn = bn0 + wn * 64 + 16 * j + r;     // C col = lane&15
      float* pp = pbase + (size_t)m * NPK + nn;
#pragma unroll
      for (int reg = 0; reg < 4; ++reg)
        pp[(size_t)reg * NPK] = acc[i][j][reg];
    }
  }
#undef STAGE3
#undef COMPUTE3
}

// Epilogue: sum 4 partials + b2, argmax both groups, flag ties, write one-hot rows.
__global__ __launch_bounds__(256) void k_epilogue(const float* __restrict__ partial,
                                                  const float* __restrict__ b2,
                                                  const int* __restrict__ tok,
                                                  int* __restrict__ win,
                                                  int* __restrict__ gcnt,
                                                  int* __restrict__ glist,
                                                  float* __restrict__ out) {
  const int b = blockIdx.x, tid = threadIdx.x;
  const int e = tid >> 1, grp = tid & 1;
  __shared__ int winS[256];
  __shared__ int flagS[256];
  float x[VOC];
  const size_t base = (size_t)b * NPK + 46 * e + 23 * grp;
#pragma unroll
  for (int c = 0; c < VOC; ++c) x[c] = b2[92 * e + 23 * grp + c];
#pragma unroll
  for (int s2 = 0; s2 < 4; ++s2) {
    const float* pp = partial + (size_t)s2 * NB * NPK + base;
#pragma unroll
    for (int c = 0; c < VOC; ++c) x[c] += pp[c];
  }
  float b0 = -1e30f, b1v = -1e30f; int bi = 0;
#pragma unroll
  for (int c = 0; c < VOC; ++c) {
    if (x[c] > b0) { b1v = b0; b0 = x[c]; bi = c; }
    else if (x[c] > b1v) b1v = x[c];
  }
  winS[tid] = bi;
  flagS[tid] = (b0 - b1v < EPS_TIE) ? 1 : 0;
  __syncthreads();
  if (!grp) {
    const int loc = winS[tid], sc = winS[tid + 1];
    win[b * 256 + 2 * e] = loc;
    win[b * 256 + 2 * e + 1] = sc;
    const int f0 = flagS[tid], f1 = flagS[tid + 1];
    if (f0 | f1) {
      int idx = atomicAdd(gcnt, 1);
      glist[idx] = e | (b << 7) | (f0 << 16) | (f1 << 17);
    }
    const int l = 2 * e;
    float* o = out + ((size_t)b * SEQ + l) * VOC;
    if (sc == 0) {
      for (int v = 0; v < VOC; ++v) o[v] = 0.f;
    } else {
      const int t = tok[b * SEQ + l];
      int dd = t - loc; if (dd < 0) dd += VOC;
      const int u = (INV23[sc] * dd) % VOC;
      for (int v = 0; v < VOC; ++v) o[v] = (v == u) ? 1.f : 0.f;
    }
  }
}

// fp64 recheck of flagged near-ties, from original fp32 h and W2. Fixed grid.
__global__ __launch_bounds__(192) void k_recheck(const float* __restrict__ h,
                                                 const float* __restrict__ W2,
                                                 const float* __restrict__ b2,
                                                 const int* __restrict__ tok,
                                                 const int* __restrict__ win,
                                                 const int* __restrict__ gcnt,
                                                 const int* __restrict__ glist,
                                                 float* __restrict__ out) {
  const int tid = threadIdx.x;
  __shared__ double dpart[184];
  __shared__ double dlog[VOC];
  __shared__ int decS[2];
  const int n = gcnt[0];
  for (int ei = blockIdx.x; ei < n; ei += 128) {
    const int ent = glist[ei];
    const int e = ent & 127, b = (ent >> 7) & 511;
    const int l = 2 * e;
#pragma unroll
    for (int grp = 0; grp < 2; ++grp) {
      if (!(ent & (1 << (16 + grp)))) {
        if (tid == 0) decS[grp] = win[b * 256 + 2 * e + grp];
      } else {
        const int col0 = 92 * e + 23 * grp;
        if (tid < 184) {
          const int c = tid >> 3, part = tid & 7;
          const float* hb = h + (size_t)b * HID;
          const size_t colc = (size_t)(col0 + c);
          double sacc[8] = {0, 0, 0, 0, 0, 0, 0, 0};
          const int kbase = part * 512;
          for (int kk = 0; kk < 512; kk += 8) {
#pragma unroll
            for (int t2 = 0; t2 < 8; ++t2) {
              const int k = kbase + kk + t2;
              sacc[t2] += (double)hb[k] * (double)W2[(size_t)k * NCOL + colc];
            }
          }
          dpart[tid] = ((sacc[0] + sacc[1]) + (sacc[2] + sacc[3])) +
                       ((sacc[4] + sacc[5]) + (sacc[6] + sacc[7]));
        }
        __syncthreads();
        if (tid < VOC) {
          double sd = (double)b2[col0 + tid];
#pragma unroll
          for (int p2 = 0; p2 < 8; ++p2) sd += dpart[tid * 8 + p2];
          dlog[tid] = sd;
        }
        __syncthreads();
        if (tid == 0) {
          double best = -1e300; int bi2 = 0;
#pragma unroll
          for (int c = 0; c < VOC; ++c)
            if (dlog[c] > best) { best = dlog[c]; bi2 = c; }
          decS[grp] = bi2;
        }
      }
      __syncthreads();
    }
    if (tid < VOC) {
      const int loc = decS[0], sc = decS[1];
      float val = 0.f;
      if (sc != 0) {
        const int t = tok[b * SEQ + l];
        int dd = t - loc; if (dd < 0) dd += VOC;
        const int u = (INV23[sc] * dd) % VOC;
        val = (tid == u) ? 1.f : 0.f;
      }
      out[((size_t)b * SEQ + l) * VOC + tid] = val;
    }
    __syncthreads();
  }
}

extern "C" void kernel_launch(void* const* d_in, const int* in_sizes, int n_in,
                              void* d_out, int out_size, void* d_ws, size_t ws_size,
                              hipStream_t stream) {
  const float* in  = (const float*)d_in[0];
  const float* W1  = (const float*)d_in[2];
  const float* b1  = (const float*)d_in[3];
  const float* W2  = (const float*)d_in[4];
  const float* b2  = (const float*)d_in[5];
  float* out = (float*)d_out;

  char* w = (char*)d_ws;
  int* tok = (int*)w;                         w += (size_t)NB * SEQ * 4;          // 0.5 MB
  float* h = (float*)w;                       w += (size_t)NB * HID * 4;          // 8 MB
  unsigned short* Ap = (unsigned short*)w;    w += (size_t)NB * KP * 2;           // 12.6 MB
  unsigned short* Bp = (unsigned short*)w;    w += (size_t)NPK * KP * 2;          // 144.7 MB
  float* partial = (float*)w;                 w += (size_t)4 * NB * NPK * 4;      // 48.2 MB
  int* win = (int*)w;                         w += (size_t)NB * 256 * 4;          // 0.5 MB
  int* gcnt = (int*)w;                        w += 256;
  int* glist = (int*)w;                       w += (size_t)65536 * 4;             // 0.26 MB

  k_tok_copy<<<dim3(NB), dim3(256), 0, stream>>>(in, out, tok);
  k_pack_w2<<<dim3(64, 92), dim3(256), 0, stream>>>(W2, Bp);
  k_hidden<<<dim3(NB), dim3(256), 0, stream>>>(W1, b1, tok, h, Ap);
  hipMemsetAsync(gcnt, 0, 4, stream);
  k3_mfma<<<dim3(184), dim3(512), 0, stream>>>(Ap, Bp, partial);
  k_epilogue<<<dim3(NB), dim3(256), 0, stream>>>(partial, b2, tok, win, gcnt, glist, out);
  k_recheck<<<dim3(128), dim3(192), 0, stream>>>(h, W2, b2, tok, win, gcnt, glist, out);
}

// Round 3
// 616.125 us; speedup vs baseline: 1.1358x; 1.0094x over previous
//
#include <hip/hip_runtime.h>
#include <cstddef>
#include <cstdint>

#define VOC 23
#define SEQ 256
#define NB  512
#define HID 4096
#define NCOL 11776    // SEQ*2*VOC
#define NPK 5888      // packed even-position cols: 128 * 46
#define KP  12288     // 3 * HID (split-bf16 triplets along K)
#define EPS_TIE 4e-5f // fp32-path net error tail <1e-5 -> 4x margin

__constant__ int INV23[VOC] = {0,1,12,8,6,14,4,10,3,18,7,21,2,16,5,20,13,19,9,17,15,11,22};

typedef __attribute__((ext_vector_type(8))) short short8;
typedef __attribute__((ext_vector_type(4))) float f32x4;

static __device__ __forceinline__ unsigned int f2bf(float f) {
  unsigned int x = __float_as_uint(f);
  return (x + 0x7fffu + ((x >> 16) & 1u)) >> 16;   // RNE, finite inputs
}
static __device__ __forceinline__ float bf2f(unsigned int u) {
  return __uint_as_float(u << 16);
}

#define GL2LDS(g, l) __builtin_amdgcn_global_load_lds(                      \
    (const __attribute__((address_space(1))) unsigned int*)(g),             \
    (__attribute__((address_space(3))) unsigned int*)(l), 16, 0, 0)

// k_front: fused {hidden (blocks 0..511) | tok/copy (512..1023) | pack_w2 (1024..6911)}.
// hidden blocks dispatched first -> co-resident with pack blocks -> the L3-bound
// W1 gather overlaps the HBM-bound W2 read / Bp write. hidden computes its own
// odd-l tokens inline (bit-identical argmax); tok[] holds even-l entries only
// (the only ones epilogue/recheck consume).
__global__ __launch_bounds__(256) void k_front(const float* __restrict__ in,
                                               float* __restrict__ out,
                                               int* __restrict__ tok,
                                               const float* __restrict__ W1,
                                               const float* __restrict__ b1,
                                               float* __restrict__ h,
                                               unsigned short* __restrict__ Ap,
                                               const float* __restrict__ W2,
                                               unsigned short* __restrict__ Bp) {
  const int bid = blockIdx.x;
  const int tid = threadIdx.x;

  if (bid < NB) {
    // ---- hidden part: h = relu(b1 + sum of 128 gathered W1 rows) + Ap triplets
    const int b = bid;
    __shared__ int rowS[128];
    if (tid < 128) {
      const int l = 2 * tid + 1;
      const float* row = in + ((size_t)b * SEQ + l) * VOC;
      int t = 0; float best = -1.0f;
#pragma unroll
      for (int v = 0; v < VOC; ++v) { float x = row[v]; if (x > best) { best = x; t = v; } }
      rowS[tid] = l * VOC + t;
    }
    __syncthreads();
    float4 acc[4];
#pragma unroll
    for (int j = 0; j < 4; ++j) acc[j] = make_float4(0.f, 0.f, 0.f, 0.f);
    for (int i = 0; i < 128; i += 2) {
      const float4* wr0 = (const float4*)(W1 + (size_t)rowS[i] * HID);
      const float4* wr1 = (const float4*)(W1 + (size_t)rowS[i + 1] * HID);
      float4 w0[4], w1[4];
#pragma unroll
      for (int j = 0; j < 4; ++j) w0[j] = wr0[tid + 256 * j];
#pragma unroll
      for (int j = 0; j < 4; ++j) w1[j] = wr1[tid + 256 * j];
#pragma unroll
      for (int j = 0; j < 4; ++j) {
        acc[j].x += w0[j].x; acc[j].y += w0[j].y; acc[j].z += w0[j].z; acc[j].w += w0[j].w;
        acc[j].x += w1[j].x; acc[j].y += w1[j].y; acc[j].z += w1[j].z; acc[j].w += w1[j].w;
      }
    }
    float4* hb = (float4*)(h + (size_t)b * HID);
    const float4* bv = (const float4*)b1;
#pragma unroll
    for (int j = 0; j < 4; ++j) {
      float4 bb = bv[tid + 256 * j];
      float4 r;
      r.x = fmaxf(acc[j].x + bb.x, 0.f);
      r.y = fmaxf(acc[j].y + bb.y, 0.f);
      r.z = fmaxf(acc[j].z + bb.z, 0.f);
      r.w = fmaxf(acc[j].w + bb.w, 0.f);
      hb[tid + 256 * j] = r;
      // split-bf16 A triplets: per elem [hi, hi, lo]
      unsigned int h0 = f2bf(r.x), L0 = f2bf(r.x - bf2f(h0));
      unsigned int h1 = f2bf(r.y), L1 = f2bf(r.y - bf2f(h1));
      unsigned int h2 = f2bf(r.z), L2 = f2bf(r.z - bf2f(h2));
      unsigned int h3 = f2bf(r.w), L3 = f2bf(r.w - bf2f(h3));
      uint2* ap = (uint2*)(((char*)Ap) + (size_t)b * (KP * 2) + 24 * (tid + 256 * j));
      ap[0] = make_uint2(h0 | (h0 << 16), L0 | (h1 << 16));
      ap[1] = make_uint2(h1 | (L1 << 16), h2 | (h2 << 16));
      ap[2] = make_uint2(L2 | (h3 << 16), h3 | (L3 << 16));
    }
  } else if (bid < 2 * NB) {
    // ---- tok/copy part: even-l token extraction + odd-row passthrough copy
    const int b = bid - NB;
    const int l = tid;
    const float* row = in + ((size_t)b * SEQ + l) * VOC;
    if (l & 1) {
      float* o = out + ((size_t)b * SEQ + l) * VOC;
#pragma unroll
      for (int v = 0; v < VOC; ++v) o[v] = row[v];
    } else {
      int t = 0; float best = -1.0f;
#pragma unroll
      for (int v = 0; v < VOC; ++v) { float x = row[v]; if (x > best) { best = x; t = v; } }
      tok[b * SEQ + l] = t;
    }
  } else {
    // ---- pack part: W2 -> Bp bf16 B^T [NPK][KP], triplets [hi, lo, hi]
    const int idx = bid - 2 * NB;
    const int k0 = (idx & 63) * 64;   // 64 k-tiles
    const int j0 = (idx >> 6) * 64;   // 92 j-tiles
    __shared__ float T[64 * 65];
#pragma unroll
    for (int it = 0; it < 16; ++it) {
      int i2 = it * 256 + tid;
      int k_l = i2 >> 6, j_l = i2 & 63;
      int j = j0 + j_l;
      int ee = j / 46, cc = j - ee * 46;          // packed j -> W2 col 92e+c
      T[j_l * 65 + k_l] = W2[(size_t)(k0 + k_l) * NCOL + 92 * ee + cc];
    }
    __syncthreads();
    const int j_l = tid >> 2, qt = tid & 3;       // 4 threads per output row
    unsigned int d[24];
#pragma unroll
    for (int pr = 0; pr < 8; ++pr) {              // 8 pairs of k = 16 k-units
      int k_l = qt * 16 + pr * 2;
      float va = T[j_l * 65 + k_l], vb = T[j_l * 65 + k_l + 1];
      unsigned int ha = f2bf(va), la = f2bf(va - bf2f(ha));
      unsigned int hb = f2bf(vb), lb = f2bf(vb - bf2f(hb));
      // elems: ha, la, ha | hb, lb, hb  (B triplet = [Bh, Bl, Bh])
      d[pr * 3 + 0] = ha | (la << 16);
      d[pr * 3 + 1] = ha | (hb << 16);
      d[pr * 3 + 2] = lb | (hb << 16);
    }
    char* dst = ((char*)Bp) + (size_t)(j0 + j_l) * (KP * 2) + 6 * k0 + 96 * qt;
#pragma unroll
    for (int u = 0; u < 6; ++u) {
      uint4 w = make_uint4(d[4 * u], d[4 * u + 1], d[4 * u + 2], d[4 * u + 3]);
      ((uint4*)dst)[u] = w;
    }
  }
}

// K3 v3: bf16 MFMA GEMM, T3+T4 deep pipeline (unchanged from round 2).
// 256x256 tile, BK=32, 512 thr (8 waves, 2M x 4N; wave tile 128x64).
// Ring-4 LDS (4 slots x [A 16KB | B 16KB] = 128KB), ONE s_barrier per K-step,
// vmcnt NEVER drained in the loop (steady-state vmcnt(8): 2 stages of 4 loads fly).
// Ledger: prologue issues stages t=0,1,2. Loop t: vmcnt(8) certifies own loads of
// stage(t) retired (in-order retire), s_barrier globalizes; ds_read frags(t);
// issue stage(t+3) into slot (t+3)&3 -- its last readers (t-1) retired their
// ds_reads before barrier(t), so no second barrier needed. Tail peels 8->4->0.
// Swizzle (round-1-verified, 0 conflicts): 2 rows per 128B line,
// gph = ((row&1)*4+q) ^ (line&7); stage source pre-swizzled, LDS dest linear.
// K accumulation order = 96 ascending K=32 slices, bit-identical to v1/v2.
__global__ __launch_bounds__(512, 2) void k3_mfma(const unsigned short* __restrict__ Ap,
                                                  const unsigned short* __restrict__ Bp,
                                                  float* __restrict__ partial) {
  __shared__ char lds3[4 * 32768];   // 4 slots: [A 16KB][B 16KB]
  const int tid = threadIdx.x;

  // 184 = 8 XCD * 23: bijective chunking; consecutive d on one XCD pair the two
  // m-tiles of each (n,s) B-panel (L2 dedup) and share ~1 s-region's A slabs.
  const int f = blockIdx.x;
  const int d = (f & 7) * 23 + (f >> 3);
  const int g = d >> 1, mi = d & 1;
  const int s = g / 23, n = g - s * 23;
  const int bm0 = mi * 256;
  const int bn0 = n * 256;
  const int kb0 = s * 6144;          // byte offset of this split's K range per row

  const int lane = tid & 63, wave = tid >> 6;
  const int wm = wave & 1, wn = wave >> 1;     // 2M x 4N wave grid
  const int r = lane & 15, q = lane >> 4;

  // Stage addressing: linear LDS granule G (uniform base + lane*16), global
  // source pre-swizzled (invert gph).  c<2: A granules, c>=2: B granules.
  size_t gsrc[4]; int gdst[4];
#pragma unroll
  for (int c = 0; c < 4; ++c) {
    const int G = (c & 1) * 512 + tid;          // 0..1023
    const int line = G >> 3, gph = G & 7;
    const int gin = gph ^ (line & 7);
    const int grow = 2 * line + (gin >> 2);     // tile row 0..255
    const int gcol = (gin & 3) << 4;            // 0/16/32/48 within 64B K-slice
    const int row0 = (c < 2 ? bm0 : bn0) + grow;
    gsrc[c] = (size_t)row0 * (KP * 2) + gcol;
    gdst[c] = G * 16;
  }

#define STAGE3(slot, kbv) do {                                                    \
    char* ldsb_ = lds3 + ((slot) << 15);                                          \
    GL2LDS(((const char*)Ap) + gsrc[0] + (kbv), ldsb_ + gdst[0]);                 \
    GL2LDS(((const char*)Ap) + gsrc[1] + (kbv), ldsb_ + gdst[1]);                 \
    GL2LDS(((const char*)Bp) + gsrc[2] + (kbv), ldsb_ + 16384 + gdst[2]);         \
    GL2LDS(((const char*)Bp) + gsrc[3] + (kbv), ldsb_ + 16384 + gdst[3]);         \
  } while (0)

  // Fragment read offsets (swizzled): row = base + 16u + r -> line&7 = (r>>1)&7
  // (per-lane constant), granule-in-row = q.
  const int gphR = (((((r & 1) << 2) | q) ^ ((r >> 1) & 7)) << 4);
  const int aoff = (wm * 64 + (r >> 1)) * 128 + gphR;   // + i*1024, i=0..7
  const int boff = (wn * 32 + (r >> 1)) * 128 + gphR;   // + j*1024, j=0..3

  f32x4 acc[8][4];
#pragma unroll
  for (int i = 0; i < 8; ++i)
#pragma unroll
    for (int j = 0; j < 4; ++j) acc[i][j] = (f32x4){0.f, 0.f, 0.f, 0.f};

#define COMPUTE3(slot) do {                                                       \
    const char* sb_ = lds3 + ((slot) << 15);                                      \
    short8 a_[8], b_[4];                                                          \
    _Pragma("unroll")                                                             \
    for (int i_ = 0; i_ < 8; ++i_)                                                \
      a_[i_] = *(const short8*)(sb_ + aoff + i_ * 1024);                          \
    _Pragma("unroll")                                                             \
    for (int j_ = 0; j_ < 4; ++j_)                                                \
      b_[j_] = *(const short8*)(sb_ + 16384 + boff + j_ * 1024);                  \
    __builtin_amdgcn_s_setprio(1);                                                \
    _Pragma("unroll")                                                             \
    for (int i_ = 0; i_ < 8; ++i_)                                                \
      _Pragma("unroll")                                                           \
      for (int j_ = 0; j_ < 4; ++j_)                                              \
        acc[i_][j_] = __builtin_amdgcn_mfma_f32_16x16x32_bf16(a_[i_], b_[j_],     \
                                                              acc[i_][j_], 0, 0, 0); \
    __builtin_amdgcn_s_setprio(0);                                                \
  } while (0)

  // Prologue: 3 stages in flight (12 loads).
  STAGE3(0, kb0);
  STAGE3(1, kb0 + 64);
  STAGE3(2, kb0 + 128);

#pragma unroll 1
  for (int t = 0; t < 93; ++t) {               // NT=96, last staged here: t=92 -> 95
    asm volatile("s_waitcnt vmcnt(8)" ::: "memory");
    __builtin_amdgcn_s_barrier();
    __builtin_amdgcn_sched_barrier(0);
    const int slot = t & 3;
    {
      const char* sb_ = lds3 + (slot << 15);
      short8 a_[8], b_[4];
#pragma unroll
      for (int i_ = 0; i_ < 8; ++i_)
        a_[i_] = *(const short8*)(sb_ + aoff + i_ * 1024);
#pragma unroll
      for (int j_ = 0; j_ < 4; ++j_)
        b_[j_] = *(const short8*)(sb_ + 16384 + boff + j_ * 1024);
      STAGE3((t + 3) & 3, kb0 + (t + 3) * 64); // hazard-free: readers of (t-1) done
      __builtin_amdgcn_s_setprio(1);
#pragma unroll
      for (int i_ = 0; i_ < 8; ++i_)
#pragma unroll
        for (int j_ = 0; j_ < 4; ++j_)
          acc[i_][j_] = __builtin_amdgcn_mfma_f32_16x16x32_bf16(a_[i_], b_[j_],
                                                                acc[i_][j_], 0, 0, 0);
      __builtin_amdgcn_s_setprio(0);
    }
  }
  // Tail peel: t = 93, 94, 95 (no more stages; drain 8 -> 4 -> 0).
  asm volatile("s_waitcnt vmcnt(8)" ::: "memory");
  __builtin_amdgcn_s_barrier();
  __builtin_amdgcn_sched_barrier(0);
  COMPUTE3(93 & 3);
  asm volatile("s_waitcnt vmcnt(4)" ::: "memory");
  __builtin_amdgcn_s_barrier();
  __builtin_amdgcn_sched_barrier(0);
  COMPUTE3(94 & 3);
  asm volatile("s_waitcnt vmcnt(0)" ::: "memory");
  __builtin_amdgcn_s_barrier();
  __builtin_amdgcn_sched_barrier(0);
  COMPUTE3(95 & 3);

  float* pbase = partial + (size_t)s * NB * NPK;
#pragma unroll
  for (int i = 0; i < 8; ++i) {
    const int m = bm0 + wm * 128 + 16 * i + 4 * q;   // C row = quad*4+reg
#pragma unroll
    for (int j = 0; j < 4; ++j) {
      const int nn = bn0 + wn * 64 + 16 * j + r;     // C col = lane&15
      float* pp = pbase + (size_t)m * NPK + nn;
#pragma unroll
      for (int reg = 0; reg < 4; ++reg)
        pp[(size_t)reg * NPK] = acc[i][j][reg];
    }
  }
#undef STAGE3
#undef COMPUTE3
}

// Epilogue: sum 4 partials + b2, argmax both groups, flag ties, write one-hot rows.
__global__ __launch_bounds__(256) void k_epilogue(const float* __restrict__ partial,
                                                  const float* __restrict__ b2,
                                                  const int* __restrict__ tok,
                                                  int* __restrict__ win,
                                                  int* __restrict__ gcnt,
                                                  int* __restrict__ glist,
                                                  float* __restrict__ out) {
  const int b = blockIdx.x, tid = threadIdx.x;
  const int e = tid >> 1, grp = tid & 1;
  __shared__ int winS[256];
  __shared__ int flagS[256];
  float x[VOC];
  const size_t base = (size_t)b * NPK + 46 * e + 23 * grp;
#pragma unroll
  for (int c = 0; c < VOC; ++c) x[c] = b2[92 * e + 23 * grp + c];
#pragma unroll
  for (int s2 = 0; s2 < 4; ++s2) {
    const float* pp = partial + (size_t)s2 * NB * NPK + base;
#pragma unroll
    for (int c = 0; c < VOC; ++c) x[c] += pp[c];
  }
  float b0 = -1e30f, b1v = -1e30f; int bi = 0;
#pragma unroll
  for (int c = 0; c < VOC; ++c) {
    if (x[c] > b0) { b1v = b0; b0 = x[c]; bi = c; }
    else if (x[c] > b1v) b1v = x[c];
  }
  winS[tid] = bi;
  flagS[tid] = (b0 - b1v < EPS_TIE) ? 1 : 0;
  __syncthreads();
  if (!grp) {
    const int loc = winS[tid], sc = winS[tid + 1];
    win[b * 256 + 2 * e] = loc;
    win[b * 256 + 2 * e + 1] = sc;
    const int f0 = flagS[tid], f1 = flagS[tid + 1];
    if (f0 | f1) {
      int idx = atomicAdd(gcnt, 1);
      glist[idx] = e | (b << 7) | (f0 << 16) | (f1 << 17);
    }
    const int l = 2 * e;
    float* o = out + ((size_t)b * SEQ + l) * VOC;
    if (sc == 0) {
      for (int v = 0; v < VOC; ++v) o[v] = 0.f;
    } else {
      const int t = tok[b * SEQ + l];
      int dd = t - loc; if (dd < 0) dd += VOC;
      const int u = (INV23[sc] * dd) % VOC;
      for (int v = 0; v < VOC; ++v) o[v] = (v == u) ? 1.f : 0.f;
    }
  }
}

// fp64 recheck of flagged near-ties, from original fp32 h and W2. Fixed grid.
__global__ __launch_bounds__(192) void k_recheck(const float* __restrict__ h,
                                                 const float* __restrict__ W2,
                                                 const float* __restrict__ b2,
                                                 const int* __restrict__ tok,
                                                 const int* __restrict__ win,
                                                 const int* __restrict__ gcnt,
                                                 const int* __restrict__ glist,
                                                 float* __restrict__ out) {
  const int tid = threadIdx.x;
  __shared__ double dpart[184];
  __shared__ double dlog[VOC];
  __shared__ int decS[2];
  const int n = gcnt[0];
  for (int ei = blockIdx.x; ei < n; ei += 128) {
    const int ent = glist[ei];
    const int e = ent & 127, b = (ent >> 7) & 511;
    const int l = 2 * e;
#pragma unroll
    for (int grp = 0; grp < 2; ++grp) {
      if (!(ent & (1 << (16 + grp)))) {
        if (tid == 0) decS[grp] = win[b * 256 + 2 * e + grp];
      } else {
        const int col0 = 92 * e + 23 * grp;
        if (tid < 184) {
          const int c = tid >> 3, part = tid & 7;
          const float* hb = h + (size_t)b * HID;
          const size_t colc = (size_t)(col0 + c);
          double sacc[8] = {0, 0, 0, 0, 0, 0, 0, 0};
          const int kbase = part * 512;
          for (int kk = 0; kk < 512; kk += 8) {
#pragma unroll
            for (int t2 = 0; t2 < 8; ++t2) {
              const int k = kbase + kk + t2;
              sacc[t2] += (double)hb[k] * (double)W2[(size_t)k * NCOL + colc];
            }
          }
          dpart[tid] = ((sacc[0] + sacc[1]) + (sacc[2] + sacc[3])) +
                       ((sacc[4] + sacc[5]) + (sacc[6] + sacc[7]));
        }
        __syncthreads();
        if (tid < VOC) {
          double sd = (double)b2[col0 + tid];
#pragma unroll
          for (int p2 = 0; p2 < 8; ++p2) sd += dpart[tid * 8 + p2];
          dlog[tid] = sd;
        }
        __syncthreads();
        if (tid == 0) {
          double best = -1e300; int bi2 = 0;
#pragma unroll
          for (int c = 0; c < VOC; ++c)
            if (dlog[c] > best) { best = dlog[c]; bi2 = c; }
          decS[grp] = bi2;
        }
      }
      __syncthreads();
    }
    if (tid < VOC) {
      const int loc = decS[0], sc = decS[1];
      float val = 0.f;
      if (sc != 0) {
        const int t = tok[b * SEQ + l];
        int dd = t - loc; if (dd < 0) dd += VOC;
        const int u = (INV23[sc] * dd) % VOC;
        val = (tid == u) ? 1.f : 0.f;
      }
      out[((size_t)b * SEQ + l) * VOC + tid] = val;
    }
    __syncthreads();
  }
}

extern "C" void kernel_launch(void* const* d_in, const int* in_sizes, int n_in,
                              void* d_out, int out_size, void* d_ws, size_t ws_size,
                              hipStream_t stream) {
  const float* in  = (const float*)d_in[0];
  const float* W1  = (const float*)d_in[2];
  const float* b1  = (const float*)d_in[3];
  const float* W2  = (const float*)d_in[4];
  const float* b2  = (const float*)d_in[5];
  float* out = (float*)d_out;

  char* w = (char*)d_ws;
  int* tok = (int*)w;                         w += (size_t)NB * SEQ * 4;          // 0.5 MB
  float* h = (float*)w;                       w += (size_t)NB * HID * 4;          // 8 MB
  unsigned short* Ap = (unsigned short*)w;    w += (size_t)NB * KP * 2;           // 12.6 MB
  unsigned short* Bp = (unsigned short*)w;    w += (size_t)NPK * KP * 2;          // 144.7 MB
  float* partial = (float*)w;                 w += (size_t)4 * NB * NPK * 4;      // 48.2 MB
  int* win = (int*)w;                         w += (size_t)NB * 256 * 4;          // 0.5 MB
  int* gcnt = (int*)w;                        w += 256;
  int* glist = (int*)w;                       w += (size_t)65536 * 4;             // 0.26 MB

  hipMemsetAsync(gcnt, 0, 4, stream);
  // fused front: 512 hidden | 512 tok/copy | 5888 pack (hidden first for overlap)
  k_front<<<dim3(2 * NB + 5888), dim3(256), 0, stream>>>(in, out, tok, W1, b1, h, Ap, W2, Bp);
  k3_mfma<<<dim3(184), dim3(512), 0, stream>>>(Ap, Bp, partial);
  k_epilogue<<<dim3(NB), dim3(256), 0, stream>>>(partial, b2, tok, win, gcnt, glist, out);
  k_recheck<<<dim3(128), dim3(192), 0, stream>>>(h, W2, b2, tok, win, gcnt, glist, out);
}

// Round 4
// 612.121 us; speedup vs baseline: 1.1433x; 1.0065x over previous
//
#include <hip/hip_runtime.h>
#include <cstddef>
#include <cstdint>

#define VOC 23
#define SEQ 256
#define NB  512
#define HID 4096
#define NCOL 11776    // SEQ*2*VOC
#define NPK 5888      // packed even-position cols: 128 * 46
#define KP  12288     // 3 * HID (split-bf16 triplets along K)
#define EPS_TIE 4e-5f // fp32-path net error tail <1e-5 -> 4x margin

__constant__ int INV23[VOC] = {0,1,12,8,6,14,4,10,3,18,7,21,2,16,5,20,13,19,9,17,15,11,22};

typedef __attribute__((ext_vector_type(8))) short short8;
typedef __attribute__((ext_vector_type(4))) float f32x4;

static __device__ __forceinline__ unsigned int f2bf(float f) {
  unsigned int x = __float_as_uint(f);
  return (x + 0x7fffu + ((x >> 16) & 1u)) >> 16;   // RNE, finite inputs
}
static __device__ __forceinline__ float bf2f(unsigned int u) {
  return __uint_as_float(u << 16);
}

#define GL2LDS(g, l) __builtin_amdgcn_global_load_lds(                      \
    (const __attribute__((address_space(1))) unsigned int*)(g),             \
    (__attribute__((address_space(3))) unsigned int*)(l), 16, 0, 0)

// K1: token extraction (even l), rowIdx emission (odd l), odd-row copy.
// rowIdx[b][i] = (2i+1)*VOC + argmax(in[b, 2i+1]) -- hoisted out of hidden.
__global__ __launch_bounds__(256) void k_tok(const float* __restrict__ in,
                                             float* __restrict__ out,
                                             int* __restrict__ tok,
                                             int* __restrict__ rowIdx) {
  const int b = blockIdx.x;
  const int l = threadIdx.x;
  const float* row = in + ((size_t)b * SEQ + l) * VOC;
  int t = 0; float best = -1.0f;
#pragma unroll
  for (int v = 0; v < VOC; ++v) { float x = row[v]; if (x > best) { best = x; t = v; } }
  if (l & 1) {
    rowIdx[b * 128 + (l >> 1)] = l * VOC + t;
    float* o = out + ((size_t)b * SEQ + l) * VOC;
#pragma unroll
    for (int v = 0; v < VOC; ++v) o[v] = row[v];
  } else {
    tok[b * SEQ + l] = t;
  }
}

// Repack W2 -> Bp bf16 B^T [NPK rows][KP cols], triplets per k: [hi, lo, hi].
// 64x64 (k x j) tile, transpose through LDS. (Runs ALONE: its 338 MB stream
// must not thrash the L2 slices k_hidden2 depends on.)
__global__ __launch_bounds__(256) void k_pack_w2(const float* __restrict__ W2,
                                                 unsigned short* __restrict__ Bp) {
  const int k0 = blockIdx.x * 64;   // 64 k-tiles
  const int j0 = blockIdx.y * 64;   // 92 j-tiles
  const int tid = threadIdx.x;
  __shared__ float T[64 * 65];
#pragma unroll
  for (int it = 0; it < 16; ++it) {
    int idx = it * 256 + tid;
    int k_l = idx >> 6, j_l = idx & 63;
    int j = j0 + j_l;
    int ee = j / 46, cc = j - ee * 46;          // packed j -> W2 col 92e+c
    T[j_l * 65 + k_l] = W2[(size_t)(k0 + k_l) * NCOL + 92 * ee + cc];
  }
  __syncthreads();
  const int j_l = tid >> 2, qt = tid & 3;       // 4 threads per output row
  unsigned int d[24];
#pragma unroll
  for (int pr = 0; pr < 8; ++pr) {              // 8 pairs of k = 16 k-units
    int k_l = qt * 16 + pr * 2;
    float va = T[j_l * 65 + k_l], vb = T[j_l * 65 + k_l + 1];
    unsigned int ha = f2bf(va), la = f2bf(va - bf2f(ha));
    unsigned int hb = f2bf(vb), lb = f2bf(vb - bf2f(hb));
    // elems: ha, la, ha | hb, lb, hb  (B triplet = [Bh, Bl, Bh])
    d[pr * 3 + 0] = ha | (la << 16);
    d[pr * 3 + 1] = ha | (hb << 16);
    d[pr * 3 + 2] = lb | (hb << 16);
  }
  char* dst = ((char*)Bp) + (size_t)(j0 + j_l) * (KP * 2) + 6 * k0 + 96 * qt;
#pragma unroll
  for (int u = 0; u < 6; ++u) {
    uint4 w = make_uint4(d[4 * u], d[4 * u + 1], d[4 * u + 2], d[4 * u + 3]);
    ((uint4*)dst)[u] = w;
  }
}

// K2 v2: L2-blocked column-slice gather.
// XCD x = blockIdx&7 (dispatch round-robin) owns cols [512x, 512x+512), done in
// 2 phases of 256 cols -> per-phase per-XCD W1 footprint = 2944 rows x 256 cols
// x 4B = 2.9 MB < 4 MB L2. Block s = blockIdx>>3 covers 8 batches; thread = 1 col.
// Adds run in the SAME ascending-l order as before (+b1 at end, relu, same f2bf)
// -> h and Ap bit-identical to prior rounds.
__global__ __launch_bounds__(256) void k_hidden2(const float* __restrict__ W1,
                                                 const float* __restrict__ b1,
                                                 const int* __restrict__ rowIdx,
                                                 float* __restrict__ h,
                                                 unsigned short* __restrict__ Ap) {
  const int tid = threadIdx.x;
  const int x = blockIdx.x & 7;        // XCD
  const int s = blockIdx.x >> 3;       // 0..63
  const int b0 = s * 8;
#pragma unroll 1
  for (int p = 0; p < 2; ++p) {
    const int col = x * 512 + p * 256 + tid;
    const float bb = b1[col];
#pragma unroll 1
    for (int bi = 0; bi < 8; ++bi) {
      const int b = b0 + bi;
      const int* rp = rowIdx + b * 128;    // block-uniform -> SMEM loads
      float acc = 0.f;
#pragma unroll 16
      for (int i = 0; i < 128; ++i)
        acc += W1[(size_t)rp[i] * HID + col];
      const float r = fmaxf(acc + bb, 0.f);
      h[(size_t)b * HID + col] = r;
      const unsigned int hi = f2bf(r), lo = f2bf(r - bf2f(hi));
      unsigned short* ap = (unsigned short*)(((char*)Ap) + (size_t)b * (KP * 2) + 6 * col);
      ap[0] = (unsigned short)hi;
      ap[1] = (unsigned short)hi;
      ap[2] = (unsigned short)lo;
    }
  }
}

// K3 v3: bf16 MFMA GEMM, T3+T4 deep pipeline (unchanged from round 2).
// 256x256 tile, BK=32, 512 thr (8 waves, 2M x 4N; wave tile 128x64).
// Ring-4 LDS (4 slots x [A 16KB | B 16KB] = 128KB), ONE s_barrier per K-step,
// vmcnt NEVER drained in the loop (steady-state vmcnt(8): 2 stages of 4 loads fly).
// Ledger: prologue issues stages t=0,1,2. Loop t: vmcnt(8) certifies own loads of
// stage(t) retired (in-order retire), s_barrier globalizes; ds_read frags(t);
// issue stage(t+3) into slot (t+3)&3 -- its last readers (t-1) retired their
// ds_reads before barrier(t), so no second barrier needed. Tail peels 8->4->0.
// Swizzle (round-1-verified, 0 conflicts): 2 rows per 128B line,
// gph = ((row&1)*4+q) ^ (line&7); stage source pre-swizzled, LDS dest linear.
// K accumulation order = 96 ascending K=32 slices, bit-identical to v1/v2.
__global__ __launch_bounds__(512, 2) void k3_mfma(const unsigned short* __restrict__ Ap,
                                                  const unsigned short* __restrict__ Bp,
                                                  float* __restrict__ partial) {
  __shared__ char lds3[4 * 32768];   // 4 slots: [A 16KB][B 16KB]
  const int tid = threadIdx.x;

  // 184 = 8 XCD * 23: bijective chunking; consecutive d on one XCD pair the two
  // m-tiles of each (n,s) B-panel (L2 dedup) and share ~1 s-region's A slabs.
  const int f = blockIdx.x;
  const int d = (f & 7) * 23 + (f >> 3);
  const int g = d >> 1, mi = d & 1;
  const int s = g / 23, n = g - s * 23;
  const int bm0 = mi * 256;
  const int bn0 = n * 256;
  const int kb0 = s * 6144;          // byte offset of this split's K range per row

  const int lane = tid & 63, wave = tid >> 6;
  const int wm = wave & 1, wn = wave >> 1;     // 2M x 4N wave grid
  const int r = lane & 15, q = lane >> 4;

  // Stage addressing: linear LDS granule G (uniform base + lane*16), global
  // source pre-swizzled (invert gph).  c<2: A granules, c>=2: B granules.
  size_t gsrc[4]; int gdst[4];
#pragma unroll
  for (int c = 0; c < 4; ++c) {
    const int G = (c & 1) * 512 + tid;          // 0..1023
    const int line = G >> 3, gph = G & 7;
    const int gin = gph ^ (line & 7);
    const int grow = 2 * line + (gin >> 2);     // tile row 0..255
    const int gcol = (gin & 3) << 4;            // 0/16/32/48 within 64B K-slice
    const int row0 = (c < 2 ? bm0 : bn0) + grow;
    gsrc[c] = (size_t)row0 * (KP * 2) + gcol;
    gdst[c] = G * 16;
  }

#define STAGE3(slot, kbv) do {                                                    \
    char* ldsb_ = lds3 + ((slot) << 15);                                          \
    GL2LDS(((const char*)Ap) + gsrc[0] + (kbv), ldsb_ + gdst[0]);                 \
    GL2LDS(((const char*)Ap) + gsrc[1] + (kbv), ldsb_ + gdst[1]);                 \
    GL2LDS(((const char*)Bp) + gsrc[2] + (kbv), ldsb_ + 16384 + gdst[2]);         \
    GL2LDS(((const char*)Bp) + gsrc[3] + (kbv), ldsb_ + 16384 + gdst[3]);         \
  } while (0)

  // Fragment read offsets (swizzled): row = base + 16u + r -> line&7 = (r>>1)&7
  // (per-lane constant), granule-in-row = q.
  const int gphR = (((((r & 1) << 2) | q) ^ ((r >> 1) & 7)) << 4);
  const int aoff = (wm * 64 + (r >> 1)) * 128 + gphR;   // + i*1024, i=0..7
  const int boff = (wn * 32 + (r >> 1)) * 128 + gphR;   // + j*1024, j=0..3

  f32x4 acc[8][4];
#pragma unroll
  for (int i = 0; i < 8; ++i)
#pragma unroll
    for (int j = 0; j < 4; ++j) acc[i][j] = (f32x4){0.f, 0.f, 0.f, 0.f};

#define COMPUTE3(slot) do {                                                       \
    const char* sb_ = lds3 + ((slot) << 15);                                      \
    short8 a_[8], b_[4];                                                          \
    _Pragma("unroll")                                                             \
    for (int i_ = 0; i_ < 8; ++i_)                                                \
      a_[i_] = *(const short8*)(sb_ + aoff + i_ * 1024);                          \
    _Pragma("unroll")                                                             \
    for (int j_ = 0; j_ < 4; ++j_)                                                \
      b_[j_] = *(const short8*)(sb_ + 16384 + boff + j_ * 1024);                  \
    __builtin_amdgcn_s_setprio(1);                                                \
    _Pragma("unroll")                                                             \
    for (int i_ = 0; i_ < 8; ++i_)                                                \
      _Pragma("unroll")                                                           \
      for (int j_ = 0; j_ < 4; ++j_)                                              \
        acc[i_][j_] = __builtin_amdgcn_mfma_f32_16x16x32_bf16(a_[i_], b_[j_],     \
                                                              acc[i_][j_], 0, 0, 0); \
    __builtin_amdgcn_s_setprio(0);                                                \
  } while (0)

  // Prologue: 3 stages in flight (12 loads).
  STAGE3(0, kb0);
  STAGE3(1, kb0 + 64);
  STAGE3(2, kb0 + 128);

#pragma unroll 1
  for (int t = 0; t < 93; ++t) {               // NT=96, last staged here: t=92 -> 95
    asm volatile("s_waitcnt vmcnt(8)" ::: "memory");
    __builtin_amdgcn_s_barrier();
    __builtin_amdgcn_sched_barrier(0);
    const int slot = t & 3;
    {
      const char* sb_ = lds3 + (slot << 15);
      short8 a_[8], b_[4];
#pragma unroll
      for (int i_ = 0; i_ < 8; ++i_)
        a_[i_] = *(const short8*)(sb_ + aoff + i_ * 1024);
#pragma unroll
      for (int j_ = 0; j_ < 4; ++j_)
        b_[j_] = *(const short8*)(sb_ + 16384 + boff + j_ * 1024);
      STAGE3((t + 3) & 3, kb0 + (t + 3) * 64); // hazard-free: readers of (t-1) done
      __builtin_amdgcn_s_setprio(1);
#pragma unroll
      for (int i_ = 0; i_ < 8; ++i_)
#pragma unroll
        for (int j_ = 0; j_ < 4; ++j_)
          acc[i_][j_] = __builtin_amdgcn_mfma_f32_16x16x32_bf16(a_[i_], b_[j_],
                                                                acc[i_][j_], 0, 0, 0);
      __builtin_amdgcn_s_setprio(0);
    }
  }
  // Tail peel: t = 93, 94, 95 (no more stages; drain 8 -> 4 -> 0).
  asm volatile("s_waitcnt vmcnt(8)" ::: "memory");
  __builtin_amdgcn_s_barrier();
  __builtin_amdgcn_sched_barrier(0);
  COMPUTE3(93 & 3);
  asm volatile("s_waitcnt vmcnt(4)" ::: "memory");
  __builtin_amdgcn_s_barrier();
  __builtin_amdgcn_sched_barrier(0);
  COMPUTE3(94 & 3);
  asm volatile("s_waitcnt vmcnt(0)" ::: "memory");
  __builtin_amdgcn_s_barrier();
  __builtin_amdgcn_sched_barrier(0);
  COMPUTE3(95 & 3);

  float* pbase = partial + (size_t)s * NB * NPK;
#pragma unroll
  for (int i = 0; i < 8; ++i) {
    const int m = bm0 + wm * 128 + 16 * i + 4 * q;   // C row = quad*4+reg
#pragma unroll
    for (int j = 0; j < 4; ++j) {
      const int nn = bn0 + wn * 64 + 16 * j + r;     // C col = lane&15
      float* pp = pbase + (size_t)m * NPK + nn;
#pragma unroll
      for (int reg = 0; reg < 4; ++reg)
        pp[(size_t)reg * NPK] = acc[i][j][reg];
    }
  }
#undef STAGE3
#undef COMPUTE3
}

// Epilogue: sum 4 partials + b2, argmax both groups, flag ties, write one-hot rows.
__global__ __launch_bounds__(256) void k_epilogue(const float* __restrict__ partial,
                                                  const float* __restrict__ b2,
                                                  const int* __restrict__ tok,
                                                  int* __restrict__ win,
                                                  int* __restrict__ gcnt,
                                                  int* __restrict__ glist,
                                                  float* __restrict__ out) {
  const int b = blockIdx.x, tid = threadIdx.x;
  const int e = tid >> 1, grp = tid & 1;
  __shared__ int winS[256];
  __shared__ int flagS[256];
  float x[VOC];
  const size_t base = (size_t)b * NPK + 46 * e + 23 * grp;
#pragma unroll
  for (int c = 0; c < VOC; ++c) x[c] = b2[92 * e + 23 * grp + c];
#pragma unroll
  for (int s2 = 0; s2 < 4; ++s2) {
    const float* pp = partial + (size_t)s2 * NB * NPK + base;
#pragma unroll
    for (int c = 0; c < VOC; ++c) x[c] += pp[c];
  }
  float b0 = -1e30f, b1v = -1e30f; int bi = 0;
#pragma unroll
  for (int c = 0; c < VOC; ++c) {
    if (x[c] > b0) { b1v = b0; b0 = x[c]; bi = c; }
    else if (x[c] > b1v) b1v = x[c];
  }
  winS[tid] = bi;
  flagS[tid] = (b0 - b1v < EPS_TIE) ? 1 : 0;
  __syncthreads();
  if (!grp) {
    const int loc = winS[tid], sc = winS[tid + 1];
    win[b * 256 + 2 * e] = loc;
    win[b * 256 + 2 * e + 1] = sc;
    const int f0 = flagS[tid], f1 = flagS[tid + 1];
    if (f0 | f1) {
      int idx = atomicAdd(gcnt, 1);
      glist[idx] = e | (b << 7) | (f0 << 16) | (f1 << 17);
    }
    const int l = 2 * e;
    float* o = out + ((size_t)b * SEQ + l) * VOC;
    if (sc == 0) {
      for (int v = 0; v < VOC; ++v) o[v] = 0.f;
    } else {
      const int t = tok[b * SEQ + l];
      int dd = t - loc; if (dd < 0) dd += VOC;
      const int u = (INV23[sc] * dd) % VOC;
      for (int v = 0; v < VOC; ++v) o[v] = (v == u) ? 1.f : 0.f;
    }
  }
}

// fp64 recheck of flagged near-ties, from original fp32 h and W2. Fixed grid.
__global__ __launch_bounds__(192) void k_recheck(const float* __restrict__ h,
                                                 const float* __restrict__ W2,
                                                 const float* __restrict__ b2,
                                                 const int* __restrict__ tok,
                                                 const int* __restrict__ win,
                                                 const int* __restrict__ gcnt,
                                                 const int* __restrict__ glist,
                                                 float* __restrict__ out) {
  const int tid = threadIdx.x;
  __shared__ double dpart[184];
  __shared__ double dlog[VOC];
  __shared__ int decS[2];
  const int n = gcnt[0];
  for (int ei = blockIdx.x; ei < n; ei += 128) {
    const int ent = glist[ei];
    const int e = ent & 127, b = (ent >> 7) & 511;
    const int l = 2 * e;
#pragma unroll
    for (int grp = 0; grp < 2; ++grp) {
      if (!(ent & (1 << (16 + grp)))) {
        if (tid == 0) decS[grp] = win[b * 256 + 2 * e + grp];
      } else {
        const int col0 = 92 * e + 23 * grp;
        if (tid < 184) {
          const int c = tid >> 3, part = tid & 7;
          const float* hb = h + (size_t)b * HID;
          const size_t colc = (size_t)(col0 + c);
          double sacc[8] = {0, 0, 0, 0, 0, 0, 0, 0};
          const int kbase = part * 512;
          for (int kk = 0; kk < 512; kk += 8) {
#pragma unroll
            for (int t2 = 0; t2 < 8; ++t2) {
              const int k = kbase + kk + t2;
              sacc[t2] += (double)hb[k] * (double)W2[(size_t)k * NCOL + colc];
            }
          }
          dpart[tid] = ((sacc[0] + sacc[1]) + (sacc[2] + sacc[3])) +
                       ((sacc[4] + sacc[5]) + (sacc[6] + sacc[7]));
        }
        __syncthreads();
        if (tid < VOC) {
          double sd = (double)b2[col0 + tid];
#pragma unroll
          for (int p2 = 0; p2 < 8; ++p2) sd += dpart[tid * 8 + p2];
          dlog[tid] = sd;
        }
        __syncthreads();
        if (tid == 0) {
          double best = -1e300; int bi2 = 0;
#pragma unroll
          for (int c = 0; c < VOC; ++c)
            if (dlog[c] > best) { best = dlog[c]; bi2 = c; }
          decS[grp] = bi2;
        }
      }
      __syncthreads();
    }
    if (tid < VOC) {
      const int loc = decS[0], sc = decS[1];
      float val = 0.f;
      if (sc != 0) {
        const int t = tok[b * SEQ + l];
        int dd = t - loc; if (dd < 0) dd += VOC;
        const int u = (INV23[sc] * dd) % VOC;
        val = (tid == u) ? 1.f : 0.f;
      }
      out[((size_t)b * SEQ + l) * VOC + tid] = val;
    }
    __syncthreads();
  }
}

extern "C" void kernel_launch(void* const* d_in, const int* in_sizes, int n_in,
                              void* d_out, int out_size, void* d_ws, size_t ws_size,
                              hipStream_t stream) {
  const float* in  = (const float*)d_in[0];
  const float* W1  = (const float*)d_in[2];
  const float* b1  = (const float*)d_in[3];
  const float* W2  = (const float*)d_in[4];
  const float* b2  = (const float*)d_in[5];
  float* out = (float*)d_out;

  char* w = (char*)d_ws;
  int* tok = (int*)w;                         w += (size_t)NB * SEQ * 4;          // 0.5 MB
  float* h = (float*)w;                       w += (size_t)NB * HID * 4;          // 8 MB
  unsigned short* Ap = (unsigned short*)w;    w += (size_t)NB * KP * 2;           // 12.6 MB
  unsigned short* Bp = (unsigned short*)w;    w += (size_t)NPK * KP * 2;          // 144.7 MB
  float* partial = (float*)w;                 w += (size_t)4 * NB * NPK * 4;      // 48.2 MB
  int* win = (int*)w;                         w += (size_t)NB * 256 * 4;          // 0.5 MB
  int* gcnt = (int*)w;                        w += 256;
  int* glist = (int*)w;                       w += (size_t)65536 * 4;             // 0.26 MB
  int* rowIdx = (int*)w;                      w += (size_t)NB * 128 * 4;          // 0.26 MB

  hipMemsetAsync(gcnt, 0, 4, stream);
  k_tok<<<dim3(NB), dim3(256), 0, stream>>>(in, out, tok, rowIdx);
  k_hidden2<<<dim3(512), dim3(256), 0, stream>>>(W1, b1, rowIdx, h, Ap);
  k_pack_w2<<<dim3(64, 92), dim3(256), 0, stream>>>(W2, Bp);
  k3_mfma<<<dim3(184), dim3(512), 0, stream>>>(Ap, Bp, partial);
  k_epilogue<<<dim3(NB), dim3(256), 0, stream>>>(partial, b2, tok, win, gcnt, glist, out);
  k_recheck<<<dim3(128), dim3(192), 0, stream>>>(h, W2, b2, tok, win, gcnt, glist, out);
}